// Round 13
// baseline (249.777 us; speedup 1.0000x reference)
//
#include <hip/hip_runtime.h>
#include <hip/hip_bf16.h>

#define GV 64
#define NCLSV 10
#define C2V 32

using short8 = __attribute__((ext_vector_type(8))) short;
using short4v = __attribute__((ext_vector_type(4))) short;
using f32x4 = __attribute__((ext_vector_type(4))) float;

__device__ __forceinline__ float lrelu(float v) { return v > 0.f ? v : 0.2f * v; }
__device__ __forceinline__ float eluf(float v) { return v > 0.f ? v : expf(v) - 1.f; }

__device__ __forceinline__ unsigned short fbf(float f) {
    unsigned u = __float_as_uint(f);
    u += 0x7fff + ((u >> 16) & 1);
    return (unsigned short)(u >> 16);
}
__device__ __forceinline__ float bff(unsigned short h) {
    return __uint_as_float((unsigned)h << 16);
}
__device__ __forceinline__ unsigned f2h(float f) {
    union { _Float16 h; unsigned short u; } cv;
    cv.h = (_Float16)f;
    return (unsigned)cv.u;
}
__device__ __forceinline__ float h2f(unsigned short u) {
    union { unsigned short u; _Float16 h; } cv;
    cv.u = u;
    return (float)cv.h;
}

__global__ void zero_kernel(int* p, int n) {
    int i = blockIdx.x * blockDim.x + threadIdx.x;
    if (i < n) p[i] = 0;
}

// ---------- W prep: transpose + bf16 for W1 (256x64) and W2 (64x32) ----------
__global__ void wprep_kernel(const float* __restrict__ W1, const float* __restrict__ W2,
                             short* __restrict__ wt, short* __restrict__ wt2) {
    int t = blockIdx.x * blockDim.x + threadIdx.x;
    for (int e = t; e < 16384; e += gridDim.x * blockDim.x) {
        int k = e >> 6, ch = e & 63;
        wt[ch * 256 + k] = (short)fbf(W1[e]);
    }
    for (int e = t; e < 2048; e += gridDim.x * blockDim.x) {
        int k = e >> 5, ch = e & 31;
        wt2[ch * 64 + k] = (short)fbf(W2[e]);
    }
}

// ---------- layer-1 GEMM via MFMA (bf16) + attention dots; writes split half-tables ----------
__global__ __launch_bounds__(256) void gemm1_mfma_kernel(
    const float* __restrict__ x, const short* __restrict__ wt,
    const float* __restrict__ as_w, const float* __restrict__ ad_w,
    unsigned short* __restrict__ h1lo, unsigned short* __restrict__ h1hi,
    float* __restrict__ as1, float* __restrict__ ad1, int N) {
    __shared__ __align__(16) short xs[32 * 256];   // 16 KB
    int b0 = blockIdx.x * 32;
    int tid = threadIdx.x;
    #pragma unroll
    for (int i = 0; i < 8; ++i) {
        int e = (tid + i * 256) * 4;
        int node = e >> 8, k = e & 255;
        float4 v = make_float4(0.f, 0.f, 0.f, 0.f);
        if (b0 + node < N) v = *(const float4*)&x[(size_t)(b0 + node) * 256 + k];
        short4v hv;
        hv[0] = (short)fbf(v.x); hv[1] = (short)fbf(v.y);
        hv[2] = (short)fbf(v.z); hv[3] = (short)fbf(v.w);
        int bo = node * 512 + k * 2;
        int sw = bo ^ ((node & 7) << 4);
        *(short4v*)((char*)xs + sw) = hv;
    }
    __syncthreads();
    int w = tid >> 6, lane = tid & 63;
    int ng = w >> 1, cg = w & 1;
    int g = lane >> 4, q = lane & 15;
    int rowb = ng * 16 + q;
    int kb = g * 8;
    f32x4 acc[2];
    acc[0] = (f32x4){0.f, 0.f, 0.f, 0.f};
    acc[1] = (f32x4){0.f, 0.f, 0.f, 0.f};
    #pragma unroll
    for (int ks = 0; ks < 8; ++ks) {
        int kk = ks * 32 + kb;
        int off = (rowb * 512 + kk * 2) ^ ((rowb & 7) << 4);
        short8 a = *(const short8*)((const char*)xs + off);
        #pragma unroll
        for (int ct = 0; ct < 2; ++ct) {
            int ch = cg * 32 + ct * 16 + q;
            short8 b = *(const short8*)(wt + ch * 256 + kk);
            acc[ct] = __builtin_amdgcn_mfma_f32_16x16x32_bf16(a, b, acc[ct], 0, 0, 0);
        }
    }
    unsigned short* dst = cg ? h1hi : h1lo;
    #pragma unroll
    for (int ct = 0; ct < 2; ++ct) {
        int chi = cg * 32 + ct * 16 + q;
        int ch32 = ct * 16 + q;
        float asw = as_w[chi], adw = ad_w[chi];
        int head = cg * 2 + ct;
        #pragma unroll
        for (int r = 0; r < 4; ++r) {
            int node = b0 + ng * 16 + g * 4 + r;
            float val = acc[ct][r];
            if (node < N) dst[(size_t)node * 32 + ch32] = fbf(val);
            float vs = val * asw, vd = val * adw;
            vs += __shfl_xor(vs, 1); vs += __shfl_xor(vs, 2);
            vs += __shfl_xor(vs, 4); vs += __shfl_xor(vs, 8);
            vd += __shfl_xor(vd, 1); vd += __shfl_xor(vd, 2);
            vd += __shfl_xor(vd, 4); vd += __shfl_xor(vd, 8);
            if (q == 0 && node < N) {
                as1[node * 4 + head] = vs;
                ad1[node * 4 + head] = vd;
            }
        }
    }
}

// ---------- CSR build ----------
__global__ __launch_bounds__(256) void bucketPre_kernel(
    const int* __restrict__ ei, int E, int EE, int* __restrict__ bcnt,
    int* __restrict__ pbase) {
    __shared__ int hist[256];
    int span = (EE + gridDim.x - 1) / gridDim.x;
    int s0 = blockIdx.x * span;
    int s1 = min(s0 + span, EE);
    hist[threadIdx.x] = 0;
    __syncthreads();
    for (int i = s0 + threadIdx.x; i < s1; i += 256) {
        int d = (i < E) ? ei[E + i] : i - E;
        atomicAdd(&hist[d >> 8], 1);
    }
    __syncthreads();
    int c = hist[threadIdx.x];
    int base = 0;
    if (c) base = atomicAdd(&bcnt[threadIdx.x], c);
    pbase[blockIdx.x * 256 + threadIdx.x] = base;
}

__global__ void bscan_kernel(const int* __restrict__ bcnt, int* __restrict__ bucketoff,
                             int* __restrict__ rowoff, int N, int EE) {
    __shared__ int wtot[4];
    int v = bcnt[threadIdx.x];
    int lane = threadIdx.x & 63, w = threadIdx.x >> 6;
    int inc = v;
    for (int o = 1; o < 64; o <<= 1) { int t = __shfl_up(inc, o); if (lane >= o) inc += t; }
    if (lane == 63) wtot[w] = inc;
    __syncthreads();
    int woff = 0;
    #pragma unroll
    for (int i = 0; i < 4; ++i) woff += (i < w) ? wtot[i] : 0;
    bucketoff[threadIdx.x + 1] = woff + inc;
    if (threadIdx.x == 0) { bucketoff[0] = 0; rowoff[N] = EE; }
}

__global__ __launch_bounds__(256) void bucketA_kernel(
    const int* __restrict__ ei, int E, int EE,
    const int* __restrict__ bucketoff, const int* __restrict__ pbase,
    int* __restrict__ bbuf) {
    __shared__ int base[256];
    __shared__ int cur[256];
    int span = (EE + gridDim.x - 1) / gridDim.x;
    int s0 = blockIdx.x * span;
    int s1 = min(s0 + span, EE);
    if (s0 >= s1) return;
    base[threadIdx.x] = bucketoff[threadIdx.x] + pbase[blockIdx.x * 256 + threadIdx.x];
    cur[threadIdx.x] = 0;
    __syncthreads();
    for (int i = s0 + threadIdx.x; i < s1; i += 256) {
        int s, d;
        if (i < E) { s = ei[i]; d = ei[E + i]; } else { s = d = i - E; }
        int b = d >> 8;
        int lr = atomicAdd(&cur[b], 1);
        bbuf[base[b] + lr] = ((d & 255) << 24) | s;
    }
}

// ---------- fill pass B: pure CSR placement ----------
__global__ __launch_bounds__(256) void bucketB_kernel(
    const int* __restrict__ bucketoff, const int* __restrict__ bbuf,
    int* __restrict__ rowoff, int* __restrict__ ssrc, int N) {
    int k = blockIdx.x;
    __shared__ int cnt[256];
    __shared__ int excl[256];
    __shared__ int cur[256];
    __shared__ int wtot[4];
    cnt[threadIdx.x] = 0; cur[threadIdx.x] = 0;
    __syncthreads();
    int lo = bucketoff[k], hi = bucketoff[k + 1];
    for (int i = lo + threadIdx.x; i < hi; i += 256)
        atomicAdd(&cnt[(bbuf[i] >> 24) & 255], 1);
    __syncthreads();
    int v = cnt[threadIdx.x];
    int lane = threadIdx.x & 63, w = threadIdx.x >> 6;
    int inc = v;
    for (int o = 1; o < 64; o <<= 1) { int t = __shfl_up(inc, o); if (lane >= o) inc += t; }
    if (lane == 63) wtot[w] = inc;
    __syncthreads();
    int woff = 0;
    #pragma unroll
    for (int i = 0; i < 4; ++i) woff += (i < w) ? wtot[i] : 0;
    int e = woff + inc - v;
    excl[threadIdx.x] = e;
    int dst = (k << 8) + threadIdx.x;
    if (dst < N) rowoff[dst] = lo + e;
    __syncthreads();
    for (int i = lo + threadIdx.x; i < hi; i += 256) {
        int pv = bbuf[i];
        int dlow = (pv >> 24) & 255;
        int lr = atomicAdd(&cur[dlow], 1);
        ssrc[lo + excl[dlow] + lr] = pv & 0xFFFFFF;
    }
}

// ---------- edge weights: wave per row, full occupancy; fp16 packed per head-pair ----------
__global__ __launch_bounds__(256) void edgew_kernel(
    const int* __restrict__ rowoff, const int* __restrict__ ssrc,
    const float* __restrict__ as1, const float* __restrict__ ad1,
    int2* __restrict__ wrecA, int2* __restrict__ wrecB, int N) {
    int wv = threadIdx.x >> 6;
    int lane = threadIdx.x & 63;
    int row = blockIdx.x * 4 + wv;
    if (row >= N) return;
    int beg = rowoff[row], end = rowoff[row + 1];
    float4 d4 = *(const float4*)&ad1[row * 4];
    for (int t = beg + lane; t < end; t += 64) {
        int s = ssrc[t];
        float4 a4 = *(const float4*)&as1[s * 4];
        float w0 = __expf(lrelu(a4.x + d4.x));
        float w1 = __expf(lrelu(a4.y + d4.y));
        float w2 = __expf(lrelu(a4.z + d4.z));
        float w3 = __expf(lrelu(a4.w + d4.w));
        wrecA[t] = make_int2(s, (int)(f2h(w0) | (f2h(w1) << 16)));
        wrecB[t] = make_int2(s, (int)(f2h(w2) | (f2h(w3) << 16)));
    }
}

// ---------- layer-1 edge pass: pure gather over an L2-resident half-table ----------
// 4 lanes per edge (co = channel oct 0..3 within the 32-ch half), 16 edges in flight.
__global__ __launch_bounds__(256) void gat1_kernel(
    const int* __restrict__ rowoff, const int2* __restrict__ wrec,
    const unsigned short* __restrict__ tab, const float* __restrict__ b1,
    unsigned short* __restrict__ h2b, int N, int ho) {
    int wv = threadIdx.x >> 6;
    int lane = threadIdx.x & 63;
    int row = blockIdx.x * 4 + wv;
    if (row >= N) return;
    int beg = rowoff[row], end = rowoff[row + 1];
    int par = lane >> 2, co = lane & 3;
    float den = 0.f;
    float a[8];
    #pragma unroll
    for (int i = 0; i < 8; ++i) a[i] = 0.f;
    for (int t = beg + par; t < end; t += 16) {
        int2 rec = wrec[t];
        unsigned wu = (unsigned)rec.y;
        float w = h2f((unsigned short)((co & 2) ? (wu >> 16) : (wu & 0xFFFFu)));
        den += w;
        short8 p = *(const short8*)&tab[(size_t)rec.x * 32 + 8 * co];
        a[0] += w * bff((unsigned short)p[0]);
        a[1] += w * bff((unsigned short)p[1]);
        a[2] += w * bff((unsigned short)p[2]);
        a[3] += w * bff((unsigned short)p[3]);
        a[4] += w * bff((unsigned short)p[4]);
        a[5] += w * bff((unsigned short)p[5]);
        a[6] += w * bff((unsigned short)p[6]);
        a[7] += w * bff((unsigned short)p[7]);
    }
    den += __shfl_xor(den, 4);
    den += __shfl_xor(den, 8);
    den += __shfl_xor(den, 16);
    den += __shfl_xor(den, 32);
    #pragma unroll
    for (int i = 0; i < 8; ++i) {
        a[i] += __shfl_xor(a[i], 4);
        a[i] += __shfl_xor(a[i], 8);
        a[i] += __shfl_xor(a[i], 16);
        a[i] += __shfl_xor(a[i], 32);
    }
    if (par == 0) {
        float r = 1.f / den;
        int cbase = (ho >> 1) * 32 + 8 * co;
        short8 o;
        #pragma unroll
        for (int i = 0; i < 8; ++i)
            o[i] = (short)fbf(eluf(a[i] * r + b1[cbase + i]));
        *(short8*)&h2b[(size_t)row * 64 + cbase] = o;
    }
}

// ---------- layer-2 GEMM via MFMA (bf16) + attention dots ----------
__global__ __launch_bounds__(256) void gemm2_mfma_kernel(
    const unsigned short* __restrict__ h2b, const short* __restrict__ wt2,
    const float* __restrict__ as_w, const float* __restrict__ ad_w,
    unsigned short* __restrict__ t2b, float* __restrict__ as2, float* __restrict__ ad2, int N) {
    __shared__ __align__(16) short xs[64 * 64];   // 8 KB
    int b0 = blockIdx.x * 64;
    int tid = threadIdx.x;
    #pragma unroll
    for (int i = 0; i < 2; ++i) {
        int e = (tid + i * 256) * 8;
        int node = e >> 6, k = e & 63;
        short8 v = (short8){0, 0, 0, 0, 0, 0, 0, 0};
        if (b0 + node < N) v = *(const short8*)&h2b[(size_t)(b0 + node) * 64 + k];
        int bo = node * 128 + k * 2;
        int sw = bo ^ ((node & 7) << 4);
        *(short8*)((char*)xs + sw) = v;
    }
    __syncthreads();
    int w = tid >> 6, lane = tid & 63;
    int g = lane >> 4, q = lane & 15;
    int rowb = w * 16 + q;
    int kb = g * 8;
    f32x4 acc[2];
    acc[0] = (f32x4){0.f, 0.f, 0.f, 0.f};
    acc[1] = (f32x4){0.f, 0.f, 0.f, 0.f};
    #pragma unroll
    for (int ks = 0; ks < 2; ++ks) {
        int kk = ks * 32 + kb;
        int off = (rowb * 128 + kk * 2) ^ ((rowb & 7) << 4);
        short8 a = *(const short8*)((const char*)xs + off);
        #pragma unroll
        for (int ct = 0; ct < 2; ++ct) {
            int ch = ct * 16 + q;
            short8 b = *(const short8*)(wt2 + ch * 64 + kk);
            acc[ct] = __builtin_amdgcn_mfma_f32_16x16x32_bf16(a, b, acc[ct], 0, 0, 0);
        }
    }
    float asw0 = as_w[q], adw0 = ad_w[q];
    float asw1 = as_w[16 + q], adw1 = ad_w[16 + q];
    #pragma unroll
    for (int r = 0; r < 4; ++r) {
        int node = b0 + w * 16 + g * 4 + r;
        float v0 = acc[0][r], v1 = acc[1][r];
        if (node < N) {
            t2b[(size_t)node * 32 + q] = fbf(v0);
            t2b[(size_t)node * 32 + 16 + q] = fbf(v1);
        }
        float vs = v0 * asw0 + v1 * asw1;
        float vd = v0 * adw0 + v1 * adw1;
        vs += __shfl_xor(vs, 1); vs += __shfl_xor(vs, 2);
        vs += __shfl_xor(vs, 4); vs += __shfl_xor(vs, 8);
        vd += __shfl_xor(vd, 1); vd += __shfl_xor(vd, 2);
        vd += __shfl_xor(vd, 4); vd += __shfl_xor(vd, 8);
        if (q == 0 && node < N) {
            as2[node] = vs;
            ad2[node] = vd;
        }
    }
}

// ---------- layer-2 edge pass: pure gather with inline exp, no LDS ----------
__global__ __launch_bounds__(256) void gat2_kernel(
    const int* __restrict__ rowoff, const int* __restrict__ ssrc,
    const float* __restrict__ as2, const float* __restrict__ ad2,
    const unsigned short* __restrict__ t2b, const float* __restrict__ b2,
    float* __restrict__ h3, int N) {
    int wv = threadIdx.x >> 6;
    int lane = threadIdx.x & 63;
    int row = blockIdx.x * 4 + wv;
    if (row >= N) return;
    int beg = rowoff[row], end = rowoff[row + 1];
    int par = lane >> 2, co = lane & 3;
    float adv = ad2[row];
    float den = 0.f;
    float a[8];
    #pragma unroll
    for (int i = 0; i < 8; ++i) a[i] = 0.f;
    for (int t = beg + par; t < end; t += 16) {
        int s0 = ssrc[t];
        float w = __expf(lrelu(as2[s0] + adv));
        den += w;
        short8 p = *(const short8*)&t2b[(size_t)s0 * 32 + 8 * co];
        a[0] += w * bff((unsigned short)p[0]);
        a[1] += w * bff((unsigned short)p[1]);
        a[2] += w * bff((unsigned short)p[2]);
        a[3] += w * bff((unsigned short)p[3]);
        a[4] += w * bff((unsigned short)p[4]);
        a[5] += w * bff((unsigned short)p[5]);
        a[6] += w * bff((unsigned short)p[6]);
        a[7] += w * bff((unsigned short)p[7]);
    }
    den += __shfl_xor(den, 4);
    den += __shfl_xor(den, 8);
    den += __shfl_xor(den, 16);
    den += __shfl_xor(den, 32);
    #pragma unroll
    for (int i = 0; i < 8; ++i) {
        a[i] += __shfl_xor(a[i], 4);
        a[i] += __shfl_xor(a[i], 8);
        a[i] += __shfl_xor(a[i], 16);
        a[i] += __shfl_xor(a[i], 32);
    }
    if (par == 0) {
        float r = 1.f / den;
        float4 o0, o1;
        o0.x = eluf(a[0] * r + b2[8 * co]);
        o0.y = eluf(a[1] * r + b2[8 * co + 1]);
        o0.z = eluf(a[2] * r + b2[8 * co + 2]);
        o0.w = eluf(a[3] * r + b2[8 * co + 3]);
        o1.x = eluf(a[4] * r + b2[8 * co + 4]);
        o1.y = eluf(a[5] * r + b2[8 * co + 5]);
        o1.z = eluf(a[6] * r + b2[8 * co + 6]);
        o1.w = eluf(a[7] * r + b2[8 * co + 7]);
        *(float4*)&h3[(size_t)row * 32 + 8 * co] = o0;
        *(float4*)&h3[(size_t)row * 32 + 8 * co + 4] = o1;
    }
}

// ---------- pooling ----------
__device__ __forceinline__ int lowerb(const int* __restrict__ a, int n, int v) {
    int lo = 0, hi = n;
    while (lo < hi) {
        int mid = (lo + hi) >> 1;
        if (a[mid] < v) lo = mid + 1; else hi = mid;
    }
    return lo;
}

__global__ __launch_bounds__(256) void pool_kernel(
    const float* __restrict__ h3, const int* __restrict__ batch,
    float* __restrict__ pooled, float* __restrict__ cnt, int N) {
    int g = blockIdx.x;
    __shared__ int bounds[2];
    if (threadIdx.x == 0) bounds[0] = lowerb(batch, N, g);
    else if (threadIdx.x == 1) bounds[1] = lowerb(batch, N, g + 1);
    __syncthreads();
    int lo = bounds[0], hi = bounds[1];
    int c = threadIdx.x & 31;
    int grp = threadIdx.x >> 5;
    float s = 0.f;
    for (int n = lo + grp; n < hi; n += 8) s += h3[(size_t)n * 32 + c];
    __shared__ float red[8][33];
    red[grp][c] = s;
    __syncthreads();
    if (grp == 0) {
        float t = 0.f;
        for (int k = 0; k < 8; ++k) t += red[k][c];
        pooled[g * C2V + c] = t;
        if (c == 0) cnt[g] = (float)(hi - lo);
    }
}

__global__ void final_kernel(const float* __restrict__ pooled, const float* __restrict__ cnt,
                             const float* __restrict__ fc_w, const float* __restrict__ fc_b,
                             float* __restrict__ out) {
    int g = threadIdx.x;
    if (g >= GV) return;
    float c = cnt[g];
    c = c > 1.f ? c : 1.f;
    float p[C2V];
    for (int j = 0; j < C2V; ++j) p[j] = pooled[g * C2V + j] / c;
    float l[NCLSV];
    float mx = -1e30f;
    for (int k = 0; k < NCLSV; ++k) {
        float acc = fc_b[k];
        for (int j = 0; j < C2V; ++j) acc += p[j] * fc_w[j * NCLSV + k];
        l[k] = acc;
        mx = fmaxf(mx, acc);
    }
    float s = 0.f;
    for (int k = 0; k < NCLSV; ++k) s += expf(l[k] - mx);
    float lse = mx + logf(s);
    for (int k = 0; k < NCLSV; ++k) out[g * NCLSV + k] = l[k] - lse;
}

extern "C" void kernel_launch(void* const* d_in, const int* in_sizes, int n_in,
                              void* d_out, int out_size, void* d_ws, size_t ws_size,
                              hipStream_t stream) {
    const float* x = (const float*)d_in[0];
    const int* ei = (const int*)d_in[1];
    const int* batch = (const int*)d_in[2];
    const float* W1 = (const float*)d_in[3];
    const float* att_src1 = (const float*)d_in[4];
    const float* att_dst1 = (const float*)d_in[5];
    const float* b1 = (const float*)d_in[6];
    const float* W2 = (const float*)d_in[7];
    const float* att_src2 = (const float*)d_in[8];
    const float* att_dst2 = (const float*)d_in[9];
    const float* b2 = (const float*)d_in[10];
    const float* fc_w = (const float*)d_in[11];
    const float* fc_b = (const float*)d_in[12];
    float* out = (float*)d_out;

    int N = in_sizes[0] / 256;
    int E = in_sizes[1] / 2;
    int EE = E + N;
    int NB = (N + 255) >> 8;

    float* ws = (float*)d_ws;
    size_t off = 0;
    int* bcnt = (int*)(ws + off);      off += 256;   // zeroed each call
    size_t zTot = off;
    int* pbase = (int*)(ws + off);     off += 1024 * 256;
    int* bucketoff = (int*)(ws + off); off += 257;
    off = (off + 3) & ~(size_t)3;
    float* pooled = ws + off;          off += (size_t)GV * C2V;
    float* cnt = ws + off;             off += (size_t)GV;
    int* rowoff = (int*)(ws + off);    off += (size_t)N + 1;
    off = (off + 3) & ~(size_t)3;
    int* bbuf = (int*)(ws + off);      off += (size_t)EE;
    int* ssrc = (int*)(ws + off);      off += (size_t)EE;
    off = (off + 3) & ~(size_t)3;
    int2* wrecA = (int2*)(ws + off);   off += (size_t)2 * EE;
    int2* wrecB = (int2*)(ws + off);   off += (size_t)2 * EE;
    short* wt = (short*)(ws + off);    off += 8192;
    short* wt2 = (short*)(ws + off);   off += 1024;
    unsigned short* h1lo = (unsigned short*)(ws + off); off += (size_t)16 * N;  // N x 32 bf16
    unsigned short* h1hi = (unsigned short*)(ws + off); off += (size_t)16 * N;
    float* as1 = ws + off;             off += (size_t)4 * N;
    float* ad1 = ws + off;             off += (size_t)4 * N;
    unsigned short* h2b = (unsigned short*)(ws + off); off += (size_t)32 * N;   // N x 64 bf16
    unsigned short* t2b = (unsigned short*)(ws + off); off += (size_t)16 * N;   // N x 32 bf16
    float* as2 = ws + off;             off += (size_t)N;
    float* ad2 = ws + off;             off += (size_t)N;
    off = (off + 3) & ~(size_t)3;
    float* h3 = ws + off;              off += (size_t)32 * N;

    zero_kernel<<<1, 256, 0, stream>>>((int*)ws, (int)zTot);
    wprep_kernel<<<9, 256, 0, stream>>>(W1, W2, wt, wt2);

    gemm1_mfma_kernel<<<(N + 31) / 32, 256, 0, stream>>>(
        x, wt, att_src1, att_dst1, h1lo, h1hi, as1, ad1, N);

    bucketPre_kernel<<<1024, 256, 0, stream>>>(ei, E, EE, bcnt, pbase);
    bscan_kernel<<<1, 256, 0, stream>>>(bcnt, bucketoff, rowoff, N, EE);
    bucketA_kernel<<<1024, 256, 0, stream>>>(ei, E, EE, bucketoff, pbase, bbuf);
    bucketB_kernel<<<NB, 256, 0, stream>>>(bucketoff, bbuf, rowoff, ssrc, N);

    // edge weights at full occupancy
    edgew_kernel<<<(N + 3) / 4, 256, 0, stream>>>(rowoff, ssrc, as1, ad1, wrecA, wrecB, N);

    // layer-1 edge pass: two lean half-passes over L2-resident half-tables
    gat1_kernel<<<(N + 3) / 4, 256, 0, stream>>>(rowoff, wrecA, h1lo, b1, h2b, N, 0);
    gat1_kernel<<<(N + 3) / 4, 256, 0, stream>>>(rowoff, wrecB, h1hi, b1, h2b, N, 2);

    gemm2_mfma_kernel<<<(N + 63) / 64, 256, 0, stream>>>(
        h2b, wt2, att_src2, att_dst2, t2b, as2, ad2, N);

    gat2_kernel<<<(N + 3) / 4, 256, 0, stream>>>(rowoff, ssrc, as2, ad2, t2b, b2, h3, N);

    pool_kernel<<<GV, 256, 0, stream>>>(h3, batch, pooled, cnt, N);
    final_kernel<<<1, 64, 0, stream>>>(pooled, cnt, fc_w, fc_b, out);
}

// Round 14
// 219.857 us; speedup vs baseline: 1.1361x; 1.1361x over previous
//
#include <hip/hip_runtime.h>
#include <hip/hip_bf16.h>

#define GV 64
#define NCLSV 10
#define C2V 32
#define CHUNK 256

using short8 = __attribute__((ext_vector_type(8))) short;
using short4v = __attribute__((ext_vector_type(4))) short;
using f32x4 = __attribute__((ext_vector_type(4))) float;

__device__ __forceinline__ float lrelu(float v) { return v > 0.f ? v : 0.2f * v; }
__device__ __forceinline__ float eluf(float v) { return v > 0.f ? v : expf(v) - 1.f; }

__device__ __forceinline__ unsigned short fbf(float f) {
    unsigned u = __float_as_uint(f);
    u += 0x7fff + ((u >> 16) & 1);
    return (unsigned short)(u >> 16);
}
__device__ __forceinline__ float bff(unsigned short h) {
    return __uint_as_float((unsigned)h << 16);
}

__global__ void zero_kernel(int* p, int n) {
    int i = blockIdx.x * blockDim.x + threadIdx.x;
    if (i < n) p[i] = 0;
}

// ---------- W prep: transpose + bf16 for W1 (256x64) and W2 (64x32) ----------
__global__ void wprep_kernel(const float* __restrict__ W1, const float* __restrict__ W2,
                             short* __restrict__ wt, short* __restrict__ wt2) {
    int t = blockIdx.x * blockDim.x + threadIdx.x;
    for (int e = t; e < 16384; e += gridDim.x * blockDim.x) {
        int k = e >> 6, ch = e & 63;
        wt[ch * 256 + k] = (short)fbf(W1[e]);
    }
    for (int e = t; e < 2048; e += gridDim.x * blockDim.x) {
        int k = e >> 5, ch = e & 31;
        wt2[ch * 64 + k] = (short)fbf(W2[e]);
    }
}

// ---------- layer-1 GEMM via MFMA (bf16) + attention dots ----------
__global__ __launch_bounds__(256) void gemm1_mfma_kernel(
    const float* __restrict__ x, const short* __restrict__ wt,
    const float* __restrict__ as_w, const float* __restrict__ ad_w,
    unsigned short* __restrict__ h1b, float* __restrict__ as1, float* __restrict__ ad1, int N) {
    __shared__ __align__(16) short xs[32 * 256];   // 16 KB
    int b0 = blockIdx.x * 32;
    int tid = threadIdx.x;
    #pragma unroll
    for (int i = 0; i < 8; ++i) {
        int e = (tid + i * 256) * 4;
        int node = e >> 8, k = e & 255;
        float4 v = make_float4(0.f, 0.f, 0.f, 0.f);
        if (b0 + node < N) v = *(const float4*)&x[(size_t)(b0 + node) * 256 + k];
        short4v hv;
        hv[0] = (short)fbf(v.x); hv[1] = (short)fbf(v.y);
        hv[2] = (short)fbf(v.z); hv[3] = (short)fbf(v.w);
        int bo = node * 512 + k * 2;
        int sw = bo ^ ((node & 7) << 4);
        *(short4v*)((char*)xs + sw) = hv;
    }
    __syncthreads();
    int w = tid >> 6, lane = tid & 63;
    int ng = w >> 1, cg = w & 1;
    int g = lane >> 4, q = lane & 15;
    int rowb = ng * 16 + q;
    int kb = g * 8;
    f32x4 acc[2];
    acc[0] = (f32x4){0.f, 0.f, 0.f, 0.f};
    acc[1] = (f32x4){0.f, 0.f, 0.f, 0.f};
    #pragma unroll
    for (int ks = 0; ks < 8; ++ks) {
        int kk = ks * 32 + kb;
        int off = (rowb * 512 + kk * 2) ^ ((rowb & 7) << 4);
        short8 a = *(const short8*)((const char*)xs + off);
        #pragma unroll
        for (int ct = 0; ct < 2; ++ct) {
            int ch = cg * 32 + ct * 16 + q;
            short8 b = *(const short8*)(wt + ch * 256 + kk);
            acc[ct] = __builtin_amdgcn_mfma_f32_16x16x32_bf16(a, b, acc[ct], 0, 0, 0);
        }
    }
    #pragma unroll
    for (int ct = 0; ct < 2; ++ct) {
        int chi = cg * 32 + ct * 16 + q;
        float asw = as_w[chi], adw = ad_w[chi];
        int head = cg * 2 + ct;
        #pragma unroll
        for (int r = 0; r < 4; ++r) {
            int node = b0 + ng * 16 + g * 4 + r;
            float val = acc[ct][r];
            if (node < N) h1b[(size_t)node * 64 + chi] = fbf(val);
            float vs = val * asw, vd = val * adw;
            vs += __shfl_xor(vs, 1); vs += __shfl_xor(vs, 2);
            vs += __shfl_xor(vs, 4); vs += __shfl_xor(vs, 8);
            vd += __shfl_xor(vd, 1); vd += __shfl_xor(vd, 2);
            vd += __shfl_xor(vd, 4); vd += __shfl_xor(vd, 8);
            if (q == 0 && node < N) {
                as1[node * 4 + head] = vs;
                ad1[node * 4 + head] = vd;
            }
        }
    }
}

// ---------- CSR build: bucket counts + per-(block,bucket) offsets ----------
__global__ __launch_bounds__(256) void bucketPre_kernel(
    const int* __restrict__ ei, int E, int EE, int* __restrict__ bcnt,
    int* __restrict__ pbase) {
    __shared__ int hist[256];
    int span = (EE + gridDim.x - 1) / gridDim.x;
    int s0 = blockIdx.x * span;
    int s1 = min(s0 + span, EE);
    hist[threadIdx.x] = 0;
    __syncthreads();
    for (int i = s0 + threadIdx.x; i < s1; i += 256) {
        int d = (i < E) ? ei[E + i] : i - E;
        atomicAdd(&hist[d >> 8], 1);
    }
    __syncthreads();
    int c = hist[threadIdx.x];
    int base = 0;
    if (c) base = atomicAdd(&bcnt[threadIdx.x], c);
    pbase[blockIdx.x * 256 + threadIdx.x] = base;
}

__global__ void bscan_kernel(const int* __restrict__ bcnt, int* __restrict__ bucketoff,
                             int* __restrict__ rowoff, int N, int EE) {
    __shared__ int wtot[4];
    int v = bcnt[threadIdx.x];
    int lane = threadIdx.x & 63, w = threadIdx.x >> 6;
    int inc = v;
    for (int o = 1; o < 64; o <<= 1) { int t = __shfl_up(inc, o); if (lane >= o) inc += t; }
    if (lane == 63) wtot[w] = inc;
    __syncthreads();
    int woff = 0;
    #pragma unroll
    for (int i = 0; i < 4; ++i) woff += (i < w) ? wtot[i] : 0;
    bucketoff[threadIdx.x + 1] = woff + inc;
    if (threadIdx.x == 0) { bucketoff[0] = 0; rowoff[N] = EE; }
}

// ---------- fill pass A: scatter to bucket regions using precomputed bases ----------
__global__ __launch_bounds__(256) void bucketA_kernel(
    const int* __restrict__ ei, int E, int EE,
    const int* __restrict__ bucketoff, const int* __restrict__ pbase,
    int* __restrict__ bbuf) {
    __shared__ int base[256];
    __shared__ int cur[256];
    int span = (EE + gridDim.x - 1) / gridDim.x;
    int s0 = blockIdx.x * span;
    int s1 = min(s0 + span, EE);
    if (s0 >= s1) return;
    base[threadIdx.x] = bucketoff[threadIdx.x] + pbase[blockIdx.x * 256 + threadIdx.x];
    cur[threadIdx.x] = 0;
    __syncthreads();
    for (int i = s0 + threadIdx.x; i < s1; i += 256) {
        int s, d;
        if (i < E) { s = ei[i]; d = ei[E + i]; } else { s = d = i - E; }
        int b = d >> 8;
        int lr = atomicAdd(&cur[b], 1);
        bbuf[base[b] + lr] = ((d & 255) << 24) | s;
    }
}

__global__ __launch_bounds__(256) void bucketB_kernel(
    const int* __restrict__ bucketoff, const int* __restrict__ bbuf,
    int* __restrict__ rowoff, int* __restrict__ ssrc, int N) {
    int k = blockIdx.x;
    __shared__ int cnt[256];
    __shared__ int excl[256];
    __shared__ int cur[256];
    __shared__ int wtot[4];
    cnt[threadIdx.x] = 0; cur[threadIdx.x] = 0;
    __syncthreads();
    int lo = bucketoff[k], hi = bucketoff[k + 1];
    for (int i = lo + threadIdx.x; i < hi; i += 256)
        atomicAdd(&cnt[(bbuf[i] >> 24) & 255], 1);
    __syncthreads();
    int v = cnt[threadIdx.x];
    int lane = threadIdx.x & 63, w = threadIdx.x >> 6;
    int inc = v;
    for (int o = 1; o < 64; o <<= 1) { int t = __shfl_up(inc, o); if (lane >= o) inc += t; }
    if (lane == 63) wtot[w] = inc;
    __syncthreads();
    int woff = 0;
    #pragma unroll
    for (int i = 0; i < 4; ++i) woff += (i < w) ? wtot[i] : 0;
    int e = woff + inc - v;
    excl[threadIdx.x] = e;
    int dst = (k << 8) + threadIdx.x;
    if (dst < N) rowoff[dst] = lo + e;
    __syncthreads();
    for (int i = lo + threadIdx.x; i < hi; i += 256) {
        int pv = bbuf[i];
        int dlow = (pv >> 24) & 255;
        int lr = atomicAdd(&cur[dlow], 1);
        ssrc[lo + excl[dlow] + lr] = pv & 0xFFFFFF;
    }
}

// ---------- fused layer-1 edge pass: no-max softmax + bf16x4 gather, 4-way parity ----------
// (scores bounded ~|4|: exp() cannot overflow fp32; softmax is shift-invariant)
__global__ __launch_bounds__(256) void gat1_kernel(
    const int* __restrict__ rowoff, const int* __restrict__ ssrc,
    const float* __restrict__ as1, const float* __restrict__ ad1,
    const unsigned short* __restrict__ h1b, const float* __restrict__ b1,
    unsigned short* __restrict__ h2b, int N) {
    __shared__ int s_s[4][CHUNK];
    __shared__ float s_w[4][4 * CHUNK];   // layout [t*4 + h]
    int wv = threadIdx.x >> 6;
    int lane = threadIdx.x & 63;
    int row = blockIdx.x * 4 + wv;
    if (row >= N) return;
    int beg = rowoff[row], end = rowoff[row + 1];
    int h = lane >> 4, j = lane & 15;     // phase A: head h, edge slot j
    int par = lane >> 4, cq = lane & 15;  // phase B: parity, channels 4cq..4cq+3
    int hq = cq >> 2;                     // head owning those channels
    float adv = ad1[row * 4 + h];
    float a0c = 0.f, a1c = 0.f, a2c = 0.f, a3c = 0.f;
    float den = 0.f;
    int* sb = s_s[wv];
    float* wb = s_w[wv];
    for (int cb = beg; cb < end; cb += CHUNK) {
        int clen = min(end - cb, CHUNK);
        // phase A: single pass, no max
        for (int t = j; t < clen; t += 16) {
            int s = ssrc[cb + t];
            if (h == 0) sb[t] = s;
            float w = __expf(lrelu(as1[s * 4 + h] + adv));
            wb[t * 4 + h] = w;
            den += w;
        }
        // phase B: bf16x4 loads, 4-way parity, 2-edge unroll, direct accumulate
        int t = par;
        for (; t + 4 < clen; t += 8) {
            int s0 = sb[t], s1 = sb[t + 4];
            float w0 = wb[t * 4 + hq], w1 = wb[(t + 4) * 4 + hq];
            short4v p0 = *(const short4v*)&h1b[(size_t)s0 * 64 + 4 * cq];
            short4v p1 = *(const short4v*)&h1b[(size_t)s1 * 64 + 4 * cq];
            a0c += w0 * bff((unsigned short)p0[0]) + w1 * bff((unsigned short)p1[0]);
            a1c += w0 * bff((unsigned short)p0[1]) + w1 * bff((unsigned short)p1[1]);
            a2c += w0 * bff((unsigned short)p0[2]) + w1 * bff((unsigned short)p1[2]);
            a3c += w0 * bff((unsigned short)p0[3]) + w1 * bff((unsigned short)p1[3]);
        }
        for (; t < clen; t += 4) {
            int s0 = sb[t];
            float w0 = wb[t * 4 + hq];
            short4v p0 = *(const short4v*)&h1b[(size_t)s0 * 64 + 4 * cq];
            a0c += w0 * bff((unsigned short)p0[0]);
            a1c += w0 * bff((unsigned short)p0[1]);
            a2c += w0 * bff((unsigned short)p0[2]);
            a3c += w0 * bff((unsigned short)p0[3]);
        }
    }
    // den: reduce within each 16-lane head group, then broadcast head hq's den
    den += __shfl_xor(den, 1);
    den += __shfl_xor(den, 2);
    den += __shfl_xor(den, 4);
    den += __shfl_xor(den, 8);
    float dd = __shfl(den, hq << 4);   // any lane of head group hq
    a0c += __shfl_xor(a0c, 16); a0c += __shfl_xor(a0c, 32);
    a1c += __shfl_xor(a1c, 16); a1c += __shfl_xor(a1c, 32);
    a2c += __shfl_xor(a2c, 16); a2c += __shfl_xor(a2c, 32);
    a3c += __shfl_xor(a3c, 16); a3c += __shfl_xor(a3c, 32);
    if (par == 0) {
        float r = 1.f / dd;
        short4v o;
        o[0] = (short)fbf(eluf(a0c * r + b1[4 * cq]));
        o[1] = (short)fbf(eluf(a1c * r + b1[4 * cq + 1]));
        o[2] = (short)fbf(eluf(a2c * r + b1[4 * cq + 2]));
        o[3] = (short)fbf(eluf(a3c * r + b1[4 * cq + 3]));
        *(short4v*)&h2b[(size_t)row * 64 + 4 * cq] = o;
    }
}

// ---------- layer-2 GEMM via MFMA (bf16) + attention dots ----------
__global__ __launch_bounds__(256) void gemm2_mfma_kernel(
    const unsigned short* __restrict__ h2b, const short* __restrict__ wt2,
    const float* __restrict__ as_w, const float* __restrict__ ad_w,
    unsigned short* __restrict__ t2b, float* __restrict__ as2, float* __restrict__ ad2, int N) {
    __shared__ __align__(16) short xs[64 * 64];   // 8 KB
    int b0 = blockIdx.x * 64;
    int tid = threadIdx.x;
    #pragma unroll
    for (int i = 0; i < 2; ++i) {
        int e = (tid + i * 256) * 8;
        int node = e >> 6, k = e & 63;
        short8 v = (short8){0, 0, 0, 0, 0, 0, 0, 0};
        if (b0 + node < N) v = *(const short8*)&h2b[(size_t)(b0 + node) * 64 + k];
        int bo = node * 128 + k * 2;
        int sw = bo ^ ((node & 7) << 4);
        *(short8*)((char*)xs + sw) = v;
    }
    __syncthreads();
    int w = tid >> 6, lane = tid & 63;
    int g = lane >> 4, q = lane & 15;
    int rowb = w * 16 + q;
    int kb = g * 8;
    f32x4 acc[2];
    acc[0] = (f32x4){0.f, 0.f, 0.f, 0.f};
    acc[1] = (f32x4){0.f, 0.f, 0.f, 0.f};
    #pragma unroll
    for (int ks = 0; ks < 2; ++ks) {
        int kk = ks * 32 + kb;
        int off = (rowb * 128 + kk * 2) ^ ((rowb & 7) << 4);
        short8 a = *(const short8*)((const char*)xs + off);
        #pragma unroll
        for (int ct = 0; ct < 2; ++ct) {
            int ch = ct * 16 + q;
            short8 b = *(const short8*)(wt2 + ch * 64 + kk);
            acc[ct] = __builtin_amdgcn_mfma_f32_16x16x32_bf16(a, b, acc[ct], 0, 0, 0);
        }
    }
    float asw0 = as_w[q], adw0 = ad_w[q];
    float asw1 = as_w[16 + q], adw1 = ad_w[16 + q];
    #pragma unroll
    for (int r = 0; r < 4; ++r) {
        int node = b0 + w * 16 + g * 4 + r;
        float v0 = acc[0][r], v1 = acc[1][r];
        if (node < N) {
            t2b[(size_t)node * 32 + q] = fbf(v0);
            t2b[(size_t)node * 32 + 16 + q] = fbf(v1);
        }
        float vs = v0 * asw0 + v1 * asw1;
        float vd = v0 * adw0 + v1 * adw1;
        vs += __shfl_xor(vs, 1); vs += __shfl_xor(vs, 2);
        vs += __shfl_xor(vs, 4); vs += __shfl_xor(vs, 8);
        vd += __shfl_xor(vd, 1); vd += __shfl_xor(vd, 2);
        vd += __shfl_xor(vd, 4); vd += __shfl_xor(vd, 8);
        if (q == 0 && node < N) {
            as2[node] = vs;
            ad2[node] = vd;
        }
    }
}

// ---------- layer-2 edge pass: pure gather with inline exp, no LDS ----------
// 4 lanes per edge (co = channel oct 0..3), 16 edges in flight per wave.
__global__ __launch_bounds__(256) void gat2_kernel(
    const int* __restrict__ rowoff, const int* __restrict__ ssrc,
    const float* __restrict__ as2, const float* __restrict__ ad2,
    const unsigned short* __restrict__ t2b, const float* __restrict__ b2,
    float* __restrict__ h3, int N) {
    int wv = threadIdx.x >> 6;
    int lane = threadIdx.x & 63;
    int row = blockIdx.x * 4 + wv;
    if (row >= N) return;
    int beg = rowoff[row], end = rowoff[row + 1];
    int par = lane >> 2, co = lane & 3;
    float adv = ad2[row];
    float den = 0.f;
    float a[8];
    #pragma unroll
    for (int i = 0; i < 8; ++i) a[i] = 0.f;
    for (int t = beg + par; t < end; t += 16) {
        int s0 = ssrc[t];
        float w = __expf(lrelu(as2[s0] + adv));
        den += w;
        short8 p = *(const short8*)&t2b[(size_t)s0 * 32 + 8 * co];
        a[0] += w * bff((unsigned short)p[0]);
        a[1] += w * bff((unsigned short)p[1]);
        a[2] += w * bff((unsigned short)p[2]);
        a[3] += w * bff((unsigned short)p[3]);
        a[4] += w * bff((unsigned short)p[4]);
        a[5] += w * bff((unsigned short)p[5]);
        a[6] += w * bff((unsigned short)p[6]);
        a[7] += w * bff((unsigned short)p[7]);
    }
    den += __shfl_xor(den, 4);
    den += __shfl_xor(den, 8);
    den += __shfl_xor(den, 16);
    den += __shfl_xor(den, 32);
    #pragma unroll
    for (int i = 0; i < 8; ++i) {
        a[i] += __shfl_xor(a[i], 4);
        a[i] += __shfl_xor(a[i], 8);
        a[i] += __shfl_xor(a[i], 16);
        a[i] += __shfl_xor(a[i], 32);
    }
    if (par == 0) {
        float r = 1.f / den;
        float4 o0, o1;
        o0.x = eluf(a[0] * r + b2[8 * co]);
        o0.y = eluf(a[1] * r + b2[8 * co + 1]);
        o0.z = eluf(a[2] * r + b2[8 * co + 2]);
        o0.w = eluf(a[3] * r + b2[8 * co + 3]);
        o1.x = eluf(a[4] * r + b2[8 * co + 4]);
        o1.y = eluf(a[5] * r + b2[8 * co + 5]);
        o1.z = eluf(a[6] * r + b2[8 * co + 6]);
        o1.w = eluf(a[7] * r + b2[8 * co + 7]);
        *(float4*)&h3[(size_t)row * 32 + 8 * co] = o0;
        *(float4*)&h3[(size_t)row * 32 + 8 * co + 4] = o1;
    }
}

// ---------- pooling ----------
__device__ __forceinline__ int lowerb(const int* __restrict__ a, int n, int v) {
    int lo = 0, hi = n;
    while (lo < hi) {
        int mid = (lo + hi) >> 1;
        if (a[mid] < v) lo = mid + 1; else hi = mid;
    }
    return lo;
}

__global__ __launch_bounds__(256) void pool_kernel(
    const float* __restrict__ h3, const int* __restrict__ batch,
    float* __restrict__ pooled, float* __restrict__ cnt, int N) {
    int g = blockIdx.x;
    __shared__ int bounds[2];
    if (threadIdx.x == 0) bounds[0] = lowerb(batch, N, g);
    else if (threadIdx.x == 1) bounds[1] = lowerb(batch, N, g + 1);
    __syncthreads();
    int lo = bounds[0], hi = bounds[1];
    int c = threadIdx.x & 31;
    int grp = threadIdx.x >> 5;
    float s = 0.f;
    for (int n = lo + grp; n < hi; n += 8) s += h3[(size_t)n * 32 + c];
    __shared__ float red[8][33];
    red[grp][c] = s;
    __syncthreads();
    if (grp == 0) {
        float t = 0.f;
        for (int k = 0; k < 8; ++k) t += red[k][c];
        pooled[g * C2V + c] = t;
        if (c == 0) cnt[g] = (float)(hi - lo);
    }
}

__global__ void final_kernel(const float* __restrict__ pooled, const float* __restrict__ cnt,
                             const float* __restrict__ fc_w, const float* __restrict__ fc_b,
                             float* __restrict__ out) {
    int g = threadIdx.x;
    if (g >= GV) return;
    float c = cnt[g];
    c = c > 1.f ? c : 1.f;
    float p[C2V];
    for (int j = 0; j < C2V; ++j) p[j] = pooled[g * C2V + j] / c;
    float l[NCLSV];
    float mx = -1e30f;
    for (int k = 0; k < NCLSV; ++k) {
        float acc = fc_b[k];
        for (int j = 0; j < C2V; ++j) acc += p[j] * fc_w[j * NCLSV + k];
        l[k] = acc;
        mx = fmaxf(mx, acc);
    }
    float s = 0.f;
    for (int k = 0; k < NCLSV; ++k) s += expf(l[k] - mx);
    float lse = mx + logf(s);
    for (int k = 0; k < NCLSV; ++k) out[g * NCLSV + k] = l[k] - lse;
}

extern "C" void kernel_launch(void* const* d_in, const int* in_sizes, int n_in,
                              void* d_out, int out_size, void* d_ws, size_t ws_size,
                              hipStream_t stream) {
    const float* x = (const float*)d_in[0];
    const int* ei = (const int*)d_in[1];
    const int* batch = (const int*)d_in[2];
    const float* W1 = (const float*)d_in[3];
    const float* att_src1 = (const float*)d_in[4];
    const float* att_dst1 = (const float*)d_in[5];
    const float* b1 = (const float*)d_in[6];
    const float* W2 = (const float*)d_in[7];
    const float* att_src2 = (const float*)d_in[8];
    const float* att_dst2 = (const float*)d_in[9];
    const float* b2 = (const float*)d_in[10];
    const float* fc_w = (const float*)d_in[11];
    const float* fc_b = (const float*)d_in[12];
    float* out = (float*)d_out;

    int N = in_sizes[0] / 256;
    int E = in_sizes[1] / 2;
    int EE = E + N;
    int NB = (N + 255) >> 8;

    float* ws = (float*)d_ws;
    size_t off = 0;
    int* bcnt = (int*)(ws + off);      off += 256;   // zeroed each call
    size_t zTot = off;
    int* pbase = (int*)(ws + off);     off += 1024 * 256;
    int* bucketoff = (int*)(ws + off); off += 257;
    off = (off + 3) & ~(size_t)3;
    float* pooled = ws + off;          off += (size_t)GV * C2V;
    float* cnt = ws + off;             off += (size_t)GV;
    int* rowoff = (int*)(ws + off);    off += (size_t)N + 1;
    off = (off + 3) & ~(size_t)3;
    int* bbuf = (int*)(ws + off);      off += (size_t)EE;
    int* ssrc = (int*)(ws + off);      off += (size_t)EE;
    short* wt = (short*)(ws + off);    off += 8192;
    short* wt2 = (short*)(ws + off);   off += 1024;
    unsigned short* h1b = (unsigned short*)(ws + off); off += (size_t)32 * N;  // N x 64 bf16
    float* as1 = ws + off;             off += (size_t)4 * N;
    float* ad1 = ws + off;             off += (size_t)4 * N;
    unsigned short* h2b = (unsigned short*)(ws + off); off += (size_t)32 * N;  // N x 64 bf16
    unsigned short* t2b = (unsigned short*)(ws + off); off += (size_t)16 * N;  // N x 32 bf16
    float* as2 = ws + off;             off += (size_t)N;
    float* ad2 = ws + off;             off += (size_t)N;
    off = (off + 3) & ~(size_t)3;
    float* h3 = ws + off;              off += (size_t)32 * N;

    zero_kernel<<<1, 256, 0, stream>>>((int*)ws, (int)zTot);
    wprep_kernel<<<9, 256, 0, stream>>>(W1, W2, wt, wt2);

    gemm1_mfma_kernel<<<(N + 31) / 32, 256, 0, stream>>>(
        x, wt, att_src1, att_dst1, h1b, as1, ad1, N);

    bucketPre_kernel<<<1024, 256, 0, stream>>>(ei, E, EE, bcnt, pbase);
    bscan_kernel<<<1, 256, 0, stream>>>(bcnt, bucketoff, rowoff, N, EE);
    bucketA_kernel<<<1024, 256, 0, stream>>>(ei, E, EE, bucketoff, pbase, bbuf);
    bucketB_kernel<<<NB, 256, 0, stream>>>(bucketoff, bbuf, rowoff, ssrc, N);

    gat1_kernel<<<(N + 3) / 4, 256, 0, stream>>>(rowoff, ssrc, as1, ad1, h1b, b1, h2b, N);

    gemm2_mfma_kernel<<<(N + 63) / 64, 256, 0, stream>>>(
        h2b, wt2, att_src2, att_dst2, t2b, as2, ad2, N);

    gat2_kernel<<<(N + 3) / 4, 256, 0, stream>>>(rowoff, ssrc, as2, ad2, t2b, b2, h3, N);

    pool_kernel<<<GV, 256, 0, stream>>>(h3, batch, pooled, cnt, N);
    final_kernel<<<1, 64, 0, stream>>>(pooled, cnt, fc_w, fc_b, out);
}

// Round 15
// 212.501 us; speedup vs baseline: 1.1754x; 1.0346x over previous
//
#include <hip/hip_runtime.h>
#include <hip/hip_bf16.h>

#define GV 64
#define NCLSV 10
#define C2V 32
#define CHUNK 256

using short8 = __attribute__((ext_vector_type(8))) short;
using short4v = __attribute__((ext_vector_type(4))) short;
using f32x4 = __attribute__((ext_vector_type(4))) float;

__device__ __forceinline__ float lrelu(float v) { return v > 0.f ? v : 0.2f * v; }
__device__ __forceinline__ float eluf(float v) { return v > 0.f ? v : expf(v) - 1.f; }

__device__ __forceinline__ unsigned short fbf(float f) {
    unsigned u = __float_as_uint(f);
    u += 0x7fff + ((u >> 16) & 1);
    return (unsigned short)(u >> 16);
}
__device__ __forceinline__ float bff(unsigned short h) {
    return __uint_as_float((unsigned)h << 16);
}

// ---------- W prep (+ bcnt zero): transpose + bf16 for W1 (256x64) and W2 (64x32) ----------
__global__ void wprep_kernel(const float* __restrict__ W1, const float* __restrict__ W2,
                             short* __restrict__ wt, short* __restrict__ wt2,
                             int* __restrict__ bcnt) {
    int t = blockIdx.x * blockDim.x + threadIdx.x;
    if (blockIdx.x == 0) bcnt[threadIdx.x] = 0;
    for (int e = t; e < 16384; e += gridDim.x * blockDim.x) {
        int k = e >> 6, ch = e & 63;
        wt[ch * 256 + k] = (short)fbf(W1[e]);
    }
    for (int e = t; e < 2048; e += gridDim.x * blockDim.x) {
        int k = e >> 5, ch = e & 31;
        wt2[ch * 64 + k] = (short)fbf(W2[e]);
    }
}

// ---------- layer-1 GEMM via MFMA (bf16) + attention dots ----------
__global__ __launch_bounds__(256) void gemm1_mfma_kernel(
    const float* __restrict__ x, const short* __restrict__ wt,
    const float* __restrict__ as_w, const float* __restrict__ ad_w,
    unsigned short* __restrict__ h1b, float* __restrict__ as1, float* __restrict__ ad1, int N) {
    __shared__ __align__(16) short xs[32 * 256];   // 16 KB
    int b0 = blockIdx.x * 32;
    int tid = threadIdx.x;
    #pragma unroll
    for (int i = 0; i < 8; ++i) {
        int e = (tid + i * 256) * 4;
        int node = e >> 8, k = e & 255;
        float4 v = make_float4(0.f, 0.f, 0.f, 0.f);
        if (b0 + node < N) v = *(const float4*)&x[(size_t)(b0 + node) * 256 + k];
        short4v hv;
        hv[0] = (short)fbf(v.x); hv[1] = (short)fbf(v.y);
        hv[2] = (short)fbf(v.z); hv[3] = (short)fbf(v.w);
        int bo = node * 512 + k * 2;
        int sw = bo ^ ((node & 7) << 4);
        *(short4v*)((char*)xs + sw) = hv;
    }
    __syncthreads();
    int w = tid >> 6, lane = tid & 63;
    int ng = w >> 1, cg = w & 1;
    int g = lane >> 4, q = lane & 15;
    int rowb = ng * 16 + q;
    int kb = g * 8;
    f32x4 acc[2];
    acc[0] = (f32x4){0.f, 0.f, 0.f, 0.f};
    acc[1] = (f32x4){0.f, 0.f, 0.f, 0.f};
    #pragma unroll
    for (int ks = 0; ks < 8; ++ks) {
        int kk = ks * 32 + kb;
        int off = (rowb * 512 + kk * 2) ^ ((rowb & 7) << 4);
        short8 a = *(const short8*)((const char*)xs + off);
        #pragma unroll
        for (int ct = 0; ct < 2; ++ct) {
            int ch = cg * 32 + ct * 16 + q;
            short8 b = *(const short8*)(wt + ch * 256 + kk);
            acc[ct] = __builtin_amdgcn_mfma_f32_16x16x32_bf16(a, b, acc[ct], 0, 0, 0);
        }
    }
    #pragma unroll
    for (int ct = 0; ct < 2; ++ct) {
        int chi = cg * 32 + ct * 16 + q;
        float asw = as_w[chi], adw = ad_w[chi];
        int head = cg * 2 + ct;
        #pragma unroll
        for (int r = 0; r < 4; ++r) {
            int node = b0 + ng * 16 + g * 4 + r;
            float val = acc[ct][r];
            if (node < N) h1b[(size_t)node * 64 + chi] = fbf(val);
            float vs = val * asw, vd = val * adw;
            vs += __shfl_xor(vs, 1); vs += __shfl_xor(vs, 2);
            vs += __shfl_xor(vs, 4); vs += __shfl_xor(vs, 8);
            vd += __shfl_xor(vd, 1); vd += __shfl_xor(vd, 2);
            vd += __shfl_xor(vd, 4); vd += __shfl_xor(vd, 8);
            if (q == 0 && node < N) {
                as1[node * 4 + head] = vs;
                ad1[node * 4 + head] = vd;
            }
        }
    }
}

// ---------- CSR build: bucket counts + per-(block,bucket) offsets ----------
__global__ __launch_bounds__(256) void bucketPre_kernel(
    const int* __restrict__ ei, int E, int EE, int* __restrict__ bcnt,
    int* __restrict__ pbase) {
    __shared__ int hist[256];
    int span = (EE + gridDim.x - 1) / gridDim.x;
    int s0 = blockIdx.x * span;
    int s1 = min(s0 + span, EE);
    hist[threadIdx.x] = 0;
    __syncthreads();
    for (int i = s0 + threadIdx.x; i < s1; i += 256) {
        int d = (i < E) ? ei[E + i] : i - E;
        atomicAdd(&hist[d >> 8], 1);
    }
    __syncthreads();
    int c = hist[threadIdx.x];
    int base = 0;
    if (c) base = atomicAdd(&bcnt[threadIdx.x], c);
    pbase[blockIdx.x * 256 + threadIdx.x] = base;
}

__global__ void bscan_kernel(const int* __restrict__ bcnt, int* __restrict__ bucketoff,
                             int* __restrict__ rowoff, int N, int EE) {
    __shared__ int wtot[4];
    int v = bcnt[threadIdx.x];
    int lane = threadIdx.x & 63, w = threadIdx.x >> 6;
    int inc = v;
    for (int o = 1; o < 64; o <<= 1) { int t = __shfl_up(inc, o); if (lane >= o) inc += t; }
    if (lane == 63) wtot[w] = inc;
    __syncthreads();
    int woff = 0;
    #pragma unroll
    for (int i = 0; i < 4; ++i) woff += (i < w) ? wtot[i] : 0;
    bucketoff[threadIdx.x + 1] = woff + inc;
    if (threadIdx.x == 0) { bucketoff[0] = 0; rowoff[N] = EE; }
}

// ---------- fill pass A: scatter to bucket regions using precomputed bases ----------
__global__ __launch_bounds__(256) void bucketA_kernel(
    const int* __restrict__ ei, int E, int EE,
    const int* __restrict__ bucketoff, const int* __restrict__ pbase,
    int* __restrict__ bbuf) {
    __shared__ int base[256];
    __shared__ int cur[256];
    int span = (EE + gridDim.x - 1) / gridDim.x;
    int s0 = blockIdx.x * span;
    int s1 = min(s0 + span, EE);
    if (s0 >= s1) return;
    base[threadIdx.x] = bucketoff[threadIdx.x] + pbase[blockIdx.x * 256 + threadIdx.x];
    cur[threadIdx.x] = 0;
    __syncthreads();
    for (int i = s0 + threadIdx.x; i < s1; i += 256) {
        int s, d;
        if (i < E) { s = ei[i]; d = ei[E + i]; } else { s = d = i - E; }
        int b = d >> 8;
        int lr = atomicAdd(&cur[b], 1);
        bbuf[base[b] + lr] = ((d & 255) << 24) | s;
    }
}

__global__ __launch_bounds__(256) void bucketB_kernel(
    const int* __restrict__ bucketoff, const int* __restrict__ bbuf,
    int* __restrict__ rowoff, int* __restrict__ ssrc, int N) {
    int k = blockIdx.x;
    __shared__ int cnt[256];
    __shared__ int excl[256];
    __shared__ int cur[256];
    __shared__ int wtot[4];
    cnt[threadIdx.x] = 0; cur[threadIdx.x] = 0;
    __syncthreads();
    int lo = bucketoff[k], hi = bucketoff[k + 1];
    for (int i = lo + threadIdx.x; i < hi; i += 256)
        atomicAdd(&cnt[(bbuf[i] >> 24) & 255], 1);
    __syncthreads();
    int v = cnt[threadIdx.x];
    int lane = threadIdx.x & 63, w = threadIdx.x >> 6;
    int inc = v;
    for (int o = 1; o < 64; o <<= 1) { int t = __shfl_up(inc, o); if (lane >= o) inc += t; }
    if (lane == 63) wtot[w] = inc;
    __syncthreads();
    int woff = 0;
    #pragma unroll
    for (int i = 0; i < 4; ++i) woff += (i < w) ? wtot[i] : 0;
    int e = woff + inc - v;
    excl[threadIdx.x] = e;
    int dst = (k << 8) + threadIdx.x;
    if (dst < N) rowoff[dst] = lo + e;
    __syncthreads();
    for (int i = lo + threadIdx.x; i < hi; i += 256) {
        int pv = bbuf[i];
        int dlow = (pv >> 24) & 255;
        int lr = atomicAdd(&cur[dlow], 1);
        ssrc[lo + excl[dlow] + lr] = pv & 0xFFFFFF;
    }
}

// ---------- fused layer-1 edge pass: no-max softmax + bf16x4 gather, 4-way parity ----------
__global__ __launch_bounds__(256) void gat1_kernel(
    const int* __restrict__ rowoff, const int* __restrict__ ssrc,
    const float* __restrict__ as1, const float* __restrict__ ad1,
    const unsigned short* __restrict__ h1b, const float* __restrict__ b1,
    unsigned short* __restrict__ h2b, int N) {
    __shared__ int s_s[4][CHUNK];
    __shared__ float s_w[4][4 * CHUNK];   // layout [t*4 + h]
    int wv = threadIdx.x >> 6;
    int lane = threadIdx.x & 63;
    int row = blockIdx.x * 4 + wv;
    if (row >= N) return;
    int beg = rowoff[row], end = rowoff[row + 1];
    int h = lane >> 4, j = lane & 15;     // phase A: head h, edge slot j
    int par = lane >> 4, cq = lane & 15;  // phase B: parity, channels 4cq..4cq+3
    int hq = cq >> 2;                     // head owning those channels
    float adv = ad1[row * 4 + h];
    float a0c = 0.f, a1c = 0.f, a2c = 0.f, a3c = 0.f;
    float den = 0.f;
    int* sb = s_s[wv];
    float* wb = s_w[wv];
    for (int cb = beg; cb < end; cb += CHUNK) {
        int clen = min(end - cb, CHUNK);
        // phase A: single pass, no max
        for (int t = j; t < clen; t += 16) {
            int s = ssrc[cb + t];
            if (h == 0) sb[t] = s;
            float w = __expf(lrelu(as1[s * 4 + h] + adv));
            wb[t * 4 + h] = w;
            den += w;
        }
        // phase B: bf16x4 loads, 4-way parity, 4-edge unroll (4 loads in flight/lane)
        int t = par;
        for (; t + 12 < clen; t += 16) {
            int s0 = sb[t], s1 = sb[t + 4], s2 = sb[t + 8], s3 = sb[t + 12];
            float w0 = wb[t * 4 + hq], w1 = wb[(t + 4) * 4 + hq];
            float w2 = wb[(t + 8) * 4 + hq], w3 = wb[(t + 12) * 4 + hq];
            short4v p0 = *(const short4v*)&h1b[(size_t)s0 * 64 + 4 * cq];
            short4v p1 = *(const short4v*)&h1b[(size_t)s1 * 64 + 4 * cq];
            short4v p2 = *(const short4v*)&h1b[(size_t)s2 * 64 + 4 * cq];
            short4v p3 = *(const short4v*)&h1b[(size_t)s3 * 64 + 4 * cq];
            a0c += (w0 * bff((unsigned short)p0[0]) + w1 * bff((unsigned short)p1[0]))
                 + (w2 * bff((unsigned short)p2[0]) + w3 * bff((unsigned short)p3[0]));
            a1c += (w0 * bff((unsigned short)p0[1]) + w1 * bff((unsigned short)p1[1]))
                 + (w2 * bff((unsigned short)p2[1]) + w3 * bff((unsigned short)p3[1]));
            a2c += (w0 * bff((unsigned short)p0[2]) + w1 * bff((unsigned short)p1[2]))
                 + (w2 * bff((unsigned short)p2[2]) + w3 * bff((unsigned short)p3[2]));
            a3c += (w0 * bff((unsigned short)p0[3]) + w1 * bff((unsigned short)p1[3]))
                 + (w2 * bff((unsigned short)p2[3]) + w3 * bff((unsigned short)p3[3]));
        }
        for (; t < clen; t += 4) {
            int s0 = sb[t];
            float w0 = wb[t * 4 + hq];
            short4v p0 = *(const short4v*)&h1b[(size_t)s0 * 64 + 4 * cq];
            a0c += w0 * bff((unsigned short)p0[0]);
            a1c += w0 * bff((unsigned short)p0[1]);
            a2c += w0 * bff((unsigned short)p0[2]);
            a3c += w0 * bff((unsigned short)p0[3]);
        }
    }
    // den: reduce within each 16-lane head group, then broadcast head hq's den
    den += __shfl_xor(den, 1);
    den += __shfl_xor(den, 2);
    den += __shfl_xor(den, 4);
    den += __shfl_xor(den, 8);
    float dd = __shfl(den, hq << 4);   // any lane of head group hq
    a0c += __shfl_xor(a0c, 16); a0c += __shfl_xor(a0c, 32);
    a1c += __shfl_xor(a1c, 16); a1c += __shfl_xor(a1c, 32);
    a2c += __shfl_xor(a2c, 16); a2c += __shfl_xor(a2c, 32);
    a3c += __shfl_xor(a3c, 16); a3c += __shfl_xor(a3c, 32);
    if (par == 0) {
        float r = 1.f / dd;
        short4v o;
        o[0] = (short)fbf(eluf(a0c * r + b1[4 * cq]));
        o[1] = (short)fbf(eluf(a1c * r + b1[4 * cq + 1]));
        o[2] = (short)fbf(eluf(a2c * r + b1[4 * cq + 2]));
        o[3] = (short)fbf(eluf(a3c * r + b1[4 * cq + 3]));
        *(short4v*)&h2b[(size_t)row * 64 + 4 * cq] = o;
    }
}

// ---------- layer-2 GEMM via MFMA (bf16) + attention dots ----------
__global__ __launch_bounds__(256) void gemm2_mfma_kernel(
    const unsigned short* __restrict__ h2b, const short* __restrict__ wt2,
    const float* __restrict__ as_w, const float* __restrict__ ad_w,
    unsigned short* __restrict__ t2b, float* __restrict__ as2, float* __restrict__ ad2, int N) {
    __shared__ __align__(16) short xs[64 * 64];   // 8 KB
    int b0 = blockIdx.x * 64;
    int tid = threadIdx.x;
    #pragma unroll
    for (int i = 0; i < 2; ++i) {
        int e = (tid + i * 256) * 8;
        int node = e >> 6, k = e & 63;
        short8 v = (short8){0, 0, 0, 0, 0, 0, 0, 0};
        if (b0 + node < N) v = *(const short8*)&h2b[(size_t)(b0 + node) * 64 + k];
        int bo = node * 128 + k * 2;
        int sw = bo ^ ((node & 7) << 4);
        *(short8*)((char*)xs + sw) = v;
    }
    __syncthreads();
    int w = tid >> 6, lane = tid & 63;
    int g = lane >> 4, q = lane & 15;
    int rowb = w * 16 + q;
    int kb = g * 8;
    f32x4 acc[2];
    acc[0] = (f32x4){0.f, 0.f, 0.f, 0.f};
    acc[1] = (f32x4){0.f, 0.f, 0.f, 0.f};
    #pragma unroll
    for (int ks = 0; ks < 2; ++ks) {
        int kk = ks * 32 + kb;
        int off = (rowb * 128 + kk * 2) ^ ((rowb & 7) << 4);
        short8 a = *(const short8*)((const char*)xs + off);
        #pragma unroll
        for (int ct = 0; ct < 2; ++ct) {
            int ch = ct * 16 + q;
            short8 b = *(const short8*)(wt2 + ch * 64 + kk);
            acc[ct] = __builtin_amdgcn_mfma_f32_16x16x32_bf16(a, b, acc[ct], 0, 0, 0);
        }
    }
    float asw0 = as_w[q], adw0 = ad_w[q];
    float asw1 = as_w[16 + q], adw1 = ad_w[16 + q];
    #pragma unroll
    for (int r = 0; r < 4; ++r) {
        int node = b0 + w * 16 + g * 4 + r;
        float v0 = acc[0][r], v1 = acc[1][r];
        if (node < N) {
            t2b[(size_t)node * 32 + q] = fbf(v0);
            t2b[(size_t)node * 32 + 16 + q] = fbf(v1);
        }
        float vs = v0 * asw0 + v1 * asw1;
        float vd = v0 * adw0 + v1 * adw1;
        vs += __shfl_xor(vs, 1); vs += __shfl_xor(vs, 2);
        vs += __shfl_xor(vs, 4); vs += __shfl_xor(vs, 8);
        vd += __shfl_xor(vd, 1); vd += __shfl_xor(vd, 2);
        vd += __shfl_xor(vd, 4); vd += __shfl_xor(vd, 8);
        if (q == 0 && node < N) {
            as2[node] = vs;
            ad2[node] = vd;
        }
    }
}

// ---------- layer-2 edge pass: pure gather with inline exp, no LDS, 2-edge unroll ----------
__global__ __launch_bounds__(256) void gat2_kernel(
    const int* __restrict__ rowoff, const int* __restrict__ ssrc,
    const float* __restrict__ as2, const float* __restrict__ ad2,
    const unsigned short* __restrict__ t2b, const float* __restrict__ b2,
    float* __restrict__ h3, int N) {
    int wv = threadIdx.x >> 6;
    int lane = threadIdx.x & 63;
    int row = blockIdx.x * 4 + wv;
    if (row >= N) return;
    int beg = rowoff[row], end = rowoff[row + 1];
    int par = lane >> 2, co = lane & 3;
    float adv = ad2[row];
    float den = 0.f;
    float a[8];
    #pragma unroll
    for (int i = 0; i < 8; ++i) a[i] = 0.f;
    int t = beg + par;
    for (; t + 16 < end; t += 32) {
        int s0 = ssrc[t], s1 = ssrc[t + 16];
        float w0 = __expf(lrelu(as2[s0] + adv));
        float w1 = __expf(lrelu(as2[s1] + adv));
        den += w0 + w1;
        short8 p0 = *(const short8*)&t2b[(size_t)s0 * 32 + 8 * co];
        short8 p1 = *(const short8*)&t2b[(size_t)s1 * 32 + 8 * co];
        #pragma unroll
        for (int i = 0; i < 8; ++i)
            a[i] += w0 * bff((unsigned short)p0[i]) + w1 * bff((unsigned short)p1[i]);
    }
    for (; t < end; t += 16) {
        int s0 = ssrc[t];
        float w = __expf(lrelu(as2[s0] + adv));
        den += w;
        short8 p = *(const short8*)&t2b[(size_t)s0 * 32 + 8 * co];
        #pragma unroll
        for (int i = 0; i < 8; ++i)
            a[i] += w * bff((unsigned short)p[i]);
    }
    den += __shfl_xor(den, 4);
    den += __shfl_xor(den, 8);
    den += __shfl_xor(den, 16);
    den += __shfl_xor(den, 32);
    #pragma unroll
    for (int i = 0; i < 8; ++i) {
        a[i] += __shfl_xor(a[i], 4);
        a[i] += __shfl_xor(a[i], 8);
        a[i] += __shfl_xor(a[i], 16);
        a[i] += __shfl_xor(a[i], 32);
    }
    if (par == 0) {
        float r = 1.f / den;
        float4 o0, o1;
        o0.x = eluf(a[0] * r + b2[8 * co]);
        o0.y = eluf(a[1] * r + b2[8 * co + 1]);
        o0.z = eluf(a[2] * r + b2[8 * co + 2]);
        o0.w = eluf(a[3] * r + b2[8 * co + 3]);
        o1.x = eluf(a[4] * r + b2[8 * co + 4]);
        o1.y = eluf(a[5] * r + b2[8 * co + 5]);
        o1.z = eluf(a[6] * r + b2[8 * co + 6]);
        o1.w = eluf(a[7] * r + b2[8 * co + 7]);
        *(float4*)&h3[(size_t)row * 32 + 8 * co] = o0;
        *(float4*)&h3[(size_t)row * 32 + 8 * co + 4] = o1;
    }
}

// ---------- pooling ----------
__device__ __forceinline__ int lowerb(const int* __restrict__ a, int n, int v) {
    int lo = 0, hi = n;
    while (lo < hi) {
        int mid = (lo + hi) >> 1;
        if (a[mid] < v) lo = mid + 1; else hi = mid;
    }
    return lo;
}

__global__ __launch_bounds__(256) void pool_kernel(
    const float* __restrict__ h3, const int* __restrict__ batch,
    float* __restrict__ pooled, float* __restrict__ cnt, int N) {
    int g = blockIdx.x;
    __shared__ int bounds[2];
    if (threadIdx.x == 0) bounds[0] = lowerb(batch, N, g);
    else if (threadIdx.x == 1) bounds[1] = lowerb(batch, N, g + 1);
    __syncthreads();
    int lo = bounds[0], hi = bounds[1];
    int c = threadIdx.x & 31;
    int grp = threadIdx.x >> 5;
    float s = 0.f;
    for (int n = lo + grp; n < hi; n += 8) s += h3[(size_t)n * 32 + c];
    __shared__ float red[8][33];
    red[grp][c] = s;
    __syncthreads();
    if (grp == 0) {
        float t = 0.f;
        for (int k = 0; k < 8; ++k) t += red[k][c];
        pooled[g * C2V + c] = t;
        if (c == 0) cnt[g] = (float)(hi - lo);
    }
}

__global__ void final_kernel(const float* __restrict__ pooled, const float* __restrict__ cnt,
                             const float* __restrict__ fc_w, const float* __restrict__ fc_b,
                             float* __restrict__ out) {
    int g = threadIdx.x;
    if (g >= GV) return;
    float c = cnt[g];
    c = c > 1.f ? c : 1.f;
    float p[C2V];
    for (int j = 0; j < C2V; ++j) p[j] = pooled[g * C2V + j] / c;
    float l[NCLSV];
    float mx = -1e30f;
    for (int k = 0; k < NCLSV; ++k) {
        float acc = fc_b[k];
        for (int j = 0; j < C2V; ++j) acc += p[j] * fc_w[j * NCLSV + k];
        l[k] = acc;
        mx = fmaxf(mx, acc);
    }
    float s = 0.f;
    for (int k = 0; k < NCLSV; ++k) s += expf(l[k] - mx);
    float lse = mx + logf(s);
    for (int k = 0; k < NCLSV; ++k) out[g * NCLSV + k] = l[k] - lse;
}

extern "C" void kernel_launch(void* const* d_in, const int* in_sizes, int n_in,
                              void* d_out, int out_size, void* d_ws, size_t ws_size,
                              hipStream_t stream) {
    const float* x = (const float*)d_in[0];
    const int* ei = (const int*)d_in[1];
    const int* batch = (const int*)d_in[2];
    const float* W1 = (const float*)d_in[3];
    const float* att_src1 = (const float*)d_in[4];
    const float* att_dst1 = (const float*)d_in[5];
    const float* b1 = (const float*)d_in[6];
    const float* W2 = (const float*)d_in[7];
    const float* att_src2 = (const float*)d_in[8];
    const float* att_dst2 = (const float*)d_in[9];
    const float* b2 = (const float*)d_in[10];
    const float* fc_w = (const float*)d_in[11];
    const float* fc_b = (const float*)d_in[12];
    float* out = (float*)d_out;

    int N = in_sizes[0] / 256;
    int E = in_sizes[1] / 2;
    int EE = E + N;
    int NB = (N + 255) >> 8;

    float* ws = (float*)d_ws;
    size_t off = 0;
    int* bcnt = (int*)(ws + off);      off += 256;   // zeroed by wprep block 0
    int* pbase = (int*)(ws + off);     off += 1024 * 256;
    int* bucketoff = (int*)(ws + off); off += 257;
    off = (off + 3) & ~(size_t)3;
    float* pooled = ws + off;          off += (size_t)GV * C2V;
    float* cnt = ws + off;             off += (size_t)GV;
    int* rowoff = (int*)(ws + off);    off += (size_t)N + 1;
    off = (off + 3) & ~(size_t)3;
    int* bbuf = (int*)(ws + off);      off += (size_t)EE;
    int* ssrc = (int*)(ws + off);      off += (size_t)EE;
    short* wt = (short*)(ws + off);    off += 8192;
    short* wt2 = (short*)(ws + off);   off += 1024;
    unsigned short* h1b = (unsigned short*)(ws + off); off += (size_t)32 * N;  // N x 64 bf16
    float* as1 = ws + off;             off += (size_t)4 * N;
    float* ad1 = ws + off;             off += (size_t)4 * N;
    unsigned short* h2b = (unsigned short*)(ws + off); off += (size_t)32 * N;  // N x 64 bf16
    unsigned short* t2b = (unsigned short*)(ws + off); off += (size_t)16 * N;  // N x 32 bf16
    float* as2 = ws + off;             off += (size_t)N;
    float* ad2 = ws + off;             off += (size_t)N;
    off = (off + 3) & ~(size_t)3;
    float* h3 = ws + off;              off += (size_t)32 * N;

    wprep_kernel<<<9, 256, 0, stream>>>(W1, W2, wt, wt2, bcnt);

    gemm1_mfma_kernel<<<(N + 31) / 32, 256, 0, stream>>>(
        x, wt, att_src1, att_dst1, h1b, as1, ad1, N);

    bucketPre_kernel<<<1024, 256, 0, stream>>>(ei, E, EE, bcnt, pbase);
    bscan_kernel<<<1, 256, 0, stream>>>(bcnt, bucketoff, rowoff, N, EE);
    bucketA_kernel<<<1024, 256, 0, stream>>>(ei, E, EE, bucketoff, pbase, bbuf);
    bucketB_kernel<<<NB, 256, 0, stream>>>(bucketoff, bbuf, rowoff, ssrc, N);

    gat1_kernel<<<(N + 3) / 4, 256, 0, stream>>>(rowoff, ssrc, as1, ad1, h1b, b1, h2b, N);

    gemm2_mfma_kernel<<<(N + 63) / 64, 256, 0, stream>>>(
        h2b, wt2, att_src2, att_dst2, t2b, as2, ad2, N);

    gat2_kernel<<<(N + 3) / 4, 256, 0, stream>>>(rowoff, ssrc, as2, ad2, t2b, b2, h3, N);

    pool_kernel<<<GV, 256, 0, stream>>>(h3, batch, pooled, cnt, N);
    final_kernel<<<1, 64, 0, stream>>>(pooled, cnt, fc_w, fc_b, out);
}